// Round 10
// baseline (662.508 us; speedup 1.0000x reference)
//
#include <hip/hip_runtime.h>
#include <math.h>

#define TILE 64
#define KC 16

typedef __attribute__((ext_vector_type(8))) short short8;
typedef __attribute__((ext_vector_type(4))) float float4v;
typedef __attribute__((ext_vector_type(4))) unsigned short ushort4v;
typedef const __attribute__((address_space(1))) void* gptr_t;
typedef __attribute__((address_space(3))) void* lptr_t;

// ---------------- workspace layout (bytes) ----------------
#define OFF_DF    0ull          // 8192*1024*4 = 33554432
#define OFF_PT    0ull          // alias: 8192*512*4 = 16777216
#define OFF_YMAX  16777216ull   // alias: 8388608
#define OFF_YMIN  25165824ull   // alias: 8388608
#define OFF_YF    0ull          // alias: 8192*1024*4 = 33554432
#define OFF_IDX   67108864ull   // 655360
#define OFF_H     67764224ull   // 8388608
#define OFF_FUSB  76152832ull   // 8192*512*2 = 8388608 (bf16 fused)
#define OFF_WFB   84541440ull   // 1024*512*2 = 1048576 (bf16 Wf)
#define OFF_XX    85590016ull   // 8192 f32 = 32768
#define OFF_STATS 85917696ull   // 24576
#define OFF_COEF  85942272ull   // 12288
#define OFF_HHI   85954560ull   // 8192*128*2 = 2097152 (bf16 hi plane, Kp<=128)
#define OFF_HLO   88051712ull   // 2097152 (bf16 lo plane)
#define OFF_WCAT  90148864ull   // 512*128*4 = 262144 (fp32 Wcat)

__device__ __forceinline__ unsigned short f2bf(float f) {
  unsigned int u = __float_as_uint(f);
  unsigned int r = (u + 0x7fffu + ((u >> 16) & 1u)) >> 16;
  return (unsigned short)r;
}
__device__ __forceinline__ float bf2f(unsigned short h) {
  return __uint_as_float((unsigned)h << 16);
}

// ---------------- fp32 tiled GEMM core: C(M,N) = A(M,K) * Bw(N,K)^T ----------------
__device__ __forceinline__ void gemm_tile_loop(
    const float* __restrict__ A, const float* __restrict__ Bw,
    int K, int lda, int ldb, int rowBase, int colBase,
    float acc[4][4], float* As, float* Bs)
{
  const int tid = threadIdx.x;
  const int tx = tid & 15, ty = tid >> 4;
  for (int k0 = 0; k0 < K; k0 += KC) {
    for (int l = 0; l < 4; ++l) {
      int flat = tid * 4 + l;           // 0..1023
      int kk = flat & (KC - 1);
      int row = flat >> 4;
      int gk = k0 + kk;
      float av = 0.f, bv = 0.f;
      if (gk < K) {
        av = A[(size_t)(rowBase + row) * lda + gk];
        bv = Bw[(size_t)(colBase + row) * ldb + gk];
      }
      As[kk * TILE + row] = av;
      Bs[kk * TILE + row] = bv;
    }
    __syncthreads();
#pragma unroll
    for (int kk = 0; kk < KC; ++kk) {
      float a0[4], b0[4];
#pragma unroll
      for (int i = 0; i < 4; ++i) a0[i] = As[kk * TILE + ty * 4 + i];
#pragma unroll
      for (int j = 0; j < 4; ++j) b0[j] = Bs[kk * TILE + tx * 4 + j];
#pragma unroll
      for (int i = 0; i < 4; ++i)
#pragma unroll
        for (int j = 0; j < 4; ++j)
          acc[i][j] = fmaf(a0[i], b0[j], acc[i][j]);
    }
    __syncthreads();
  }
}

// ---------------- K0: squared norms per point (f32, prefilter only) ----------------
__global__ __launch_bounds__(256) void xxf_kernel(const float* __restrict__ H, int C,
                                                  float* __restrict__ xx) {
  int m = blockIdx.x * 256 + threadIdx.x;
  if (m < 8192) {
    float s = 0.f;
    for (int c = 0; c < C; ++c) { float h = H[(size_t)m * C + c]; s = fmaf(h, h, s); }
    xx[m] = s;
  }
}

// ---------------- K0b: split H into bf16 hi + lo planes, zero-padded to Kp ----------------
__global__ __launch_bounds__(256) void split_bf16(const float* __restrict__ H, int C, int l2kp,
                                                  unsigned short* __restrict__ hi,
                                                  unsigned short* __restrict__ lo) {
  int i = blockIdx.x * 256 + threadIdx.x;       // over 8192 << l2kp
  int m = i >> l2kp;
  int c = i & ((1 << l2kp) - 1);
  unsigned short h = 0, l = 0;
  if (c < C) {
    float v = H[(size_t)m * C + c];
    h = f2bf(v);
    l = f2bf(v - bf2f(h));
  }
  hi[i] = h;
  lo[i] = l;
}

// ---------------- K1: Gram via split-bf16 MFMA (3 passes) -> neg sq dist (prefilter) ------
__global__ __launch_bounds__(256) void dist_mfma(const unsigned short* __restrict__ Hhi,
                                                 const unsigned short* __restrict__ Hlo,
                                                 const float* __restrict__ xx,
                                                 float* __restrict__ Df, int Kp) {
  __shared__ unsigned short Ash[128 * 32], Asl[128 * 32];
  __shared__ unsigned short Bsh[128 * 32], Bsl[128 * 32];
  const int tid = threadIdx.x;
  const int lane = tid & 63;
  const int w = tid >> 6;
  const int wm = w >> 1, wn = w & 1;
  const int bz = blockIdx.z;
  const int rowBase = bz * 1024 + blockIdx.y * 128;
  const int colBase = bz * 1024 + blockIdx.x * 128;
  const int quad = lane >> 4;
  const int l15 = lane & 15;

  float4v acc[4][4] = {};

  for (int k0 = 0; k0 < Kp; k0 += 32) {
#pragma unroll
    for (int q = 0; q < 2; ++q) {
      int ch = (w * 2 + q) * 64 + lane;          // 0..511 16B-chunks per tile
      int r = ch >> 2, cp = ch & 3;
      size_t offA = (size_t)(rowBase + r) * Kp + k0 + cp * 8;
      size_t offB = (size_t)(colBase + r) * Kp + k0 + cp * 8;
      int seg = (w * 2 + q) * 512;
      __builtin_amdgcn_global_load_lds((gptr_t)(Hhi + offA), (lptr_t)(Ash + seg), 16, 0, 0);
      __builtin_amdgcn_global_load_lds((gptr_t)(Hlo + offA), (lptr_t)(Asl + seg), 16, 0, 0);
      __builtin_amdgcn_global_load_lds((gptr_t)(Hhi + offB), (lptr_t)(Bsh + seg), 16, 0, 0);
      __builtin_amdgcn_global_load_lds((gptr_t)(Hlo + offB), (lptr_t)(Bsl + seg), 16, 0, 0);
    }
    __syncthreads();
    short8 ah[4], al[4], bh[4], bl[4];
#pragma unroll
    for (int mi = 0; mi < 4; ++mi) {
      int ro = (wm * 64 + mi * 16 + l15) * 32 + quad * 8;
      ah[mi] = *(const short8*)(Ash + ro);
      al[mi] = *(const short8*)(Asl + ro);
    }
#pragma unroll
    for (int ni = 0; ni < 4; ++ni) {
      int ro = (wn * 64 + ni * 16 + l15) * 32 + quad * 8;
      bh[ni] = *(const short8*)(Bsh + ro);
      bl[ni] = *(const short8*)(Bsl + ro);
    }
#pragma unroll
    for (int mi = 0; mi < 4; ++mi)
#pragma unroll
      for (int ni = 0; ni < 4; ++ni) {
        acc[mi][ni] = __builtin_amdgcn_mfma_f32_16x16x32_bf16(ah[mi], bh[ni], acc[mi][ni], 0, 0, 0);
        acc[mi][ni] = __builtin_amdgcn_mfma_f32_16x16x32_bf16(ah[mi], bl[ni], acc[mi][ni], 0, 0, 0);
        acc[mi][ni] = __builtin_amdgcn_mfma_f32_16x16x32_bf16(al[mi], bh[ni], acc[mi][ni], 0, 0, 0);
      }
    __syncthreads();
  }
#pragma unroll
  for (int mi = 0; mi < 4; ++mi)
#pragma unroll
    for (int ni = 0; ni < 4; ++ni)
#pragma unroll
      for (int r = 0; r < 4; ++r) {
        int gm = rowBase + wm * 64 + mi * 16 + quad * 4 + r;            // global row
        int gn = blockIdx.x * 128 + wn * 64 + ni * 16 + l15;            // col in batch
        float v = 2.0f * acc[mi][ni][r] - xx[gm] - xx[bz * 1024 + gn];
        Df[(size_t)gm * 1024 + gn] = v;
      }
}

// ---------------- K2: threshold-bisection top-[32..64] superset + exact f64 rank -> top-20 set ----
template<int C>
__global__ __launch_bounds__(256) void topk_rerank(const float* __restrict__ Df,
                                                   const float* __restrict__ H,
                                                   int* __restrict__ idx) {
  __shared__ int    candLds[4][64];
  __shared__ double ndLds[4][64];
  __shared__ int    colLds[4][64];
  const int lane = threadIdx.x & 63;
  const int w = threadIdx.x >> 6;
  const int row = blockIdx.x * 4 + w;              // 0..8191
  const int b = row >> 10;
  const float* drow = Df + (size_t)row * 1024;

  unsigned s[16];
#pragma unroll
  for (int q = 0; q < 4; ++q) {
    float4v v = *(const float4v*)(drow + 256 * q + 4 * lane);
#pragma unroll
    for (int r = 0; r < 4; ++r) {
      unsigned u = __float_as_uint(v[r]);
      s[q * 4 + r] = (u & 0x80000000u) ? ~u : (u | 0x80000000u);
    }
  }

  unsigned p = 0;
  for (int bit = 31; bit >= 0; --bit) {
    unsigned cand = p | (1u << bit);
    int c = 0;
#pragma unroll
    for (int t = 0; t < 16; ++t)
      c += __popcll(__ballot(s[t] > cand));
    if (c >= 32) {
      p = cand;
      if (c <= 64) break;
    }
  }

  const unsigned long long lt = (1ull << lane) - 1ull;
  int base = 0;
#pragma unroll
  for (int t = 0; t < 16; ++t) {
    unsigned long long m = __ballot(s[t] > p);
    if (s[t] > p) {
      int slot = base + (int)__popcll(m & lt);
      if (slot < 64) candLds[w][slot] = 256 * (t >> 2) + 4 * lane + (t & 3);
    }
    base += (int)__popcll(m);
  }
  int nsel = base > 64 ? 64 : base;

  double nd; int col;
  if (lane < nsel) {
    col = candLds[w][lane];
    const float* xi = H + (size_t)row * C;
    const float* xj = H + (size_t)(b * 1024 + col) * C;
    double ssum = 0.0;
    if (C == 3) {
#pragma unroll
      for (int c = 0; c < 3; ++c) {
        double d = (double)xi[c] - (double)xj[c];
        ssum = fma(d, d, ssum);
      }
    } else {
      for (int c = 0; c < C; c += 4) {
        float4v a = *(const float4v*)(xi + c);
        float4v bb = *(const float4v*)(xj + c);
        double d0 = (double)a.x - (double)bb.x;
        double d1 = (double)a.y - (double)bb.y;
        double d2 = (double)a.z - (double)bb.z;
        double d3 = (double)a.w - (double)bb.w;
        ssum = fma(d0, d0, ssum); ssum = fma(d1, d1, ssum);
        ssum = fma(d2, d2, ssum); ssum = fma(d3, d3, ssum);
      }
    }
    nd = -ssum;
  } else {
    nd = -INFINITY; col = 100000 + lane;
  }
  ndLds[w][lane] = nd;
  colLds[w][lane] = col;

  int rank = 0;
#pragma unroll 4
  for (int j = 0; j < 64; ++j) {
    double vj = ndLds[w][j];
    int cj = colLds[w][j];
    rank += (vj > nd || (vj == nd && cj < col)) ? 1 : 0;
  }
  if (rank < 20) idx[(size_t)row * 20 + rank] = col;
}

// ---------------- K3a: Wcat = [W1 ; W2-W1]  (W is (out, 2C) row-major, fp32) ----------------
__global__ __launch_bounds__(256) void wcat_kernel(const float* __restrict__ W,
                                                   float* __restrict__ Wcat, int outc, int C) {
  int i = blockIdx.x * 256 + threadIdx.x;
  if (i < outc * C) {
    int o = i / C, c = i % C;
    float w1 = W[(size_t)o * 2 * C + c];
    float w2 = W[(size_t)o * 2 * C + C + c];
    Wcat[(size_t)o * C + c] = w1;
    Wcat[(size_t)(outc + o) * C + c] = w2 - w1;
  }
}

// ---------------- K3b: PT(M, 2*out) = H(M,C) @ Wcat^T (fp32 — H fidelity critical) ---------
__global__ __launch_bounds__(256) void pt_gemm(const float* __restrict__ A,
                                               const float* __restrict__ Bw,
                                               float* __restrict__ Out, int K, int Nn) {
  __shared__ float As[KC * TILE], Bs[KC * TILE];
  int rowBase = blockIdx.y * 64, colBase = blockIdx.x * 64;
  float acc[4][4] = {};
  gemm_tile_loop(A, Bw, K, K, K, rowBase, colBase, acc, As, Bs);
  int tx = threadIdx.x & 15, ty = threadIdx.x >> 4;
#pragma unroll
  for (int i = 0; i < 4; ++i)
#pragma unroll
    for (int j = 0; j < 4; ++j)
      Out[(size_t)(rowBase + ty * 4 + i) * Nn + colBase + tx * 4 + j] = acc[i][j];
}

// ---------------- K4: gather + max/min over k + channel stats (float4 over channels) -------
__global__ __launch_bounds__(256) void edge_reduce(const float* __restrict__ PT,
                                                   const int* __restrict__ idx,
                                                   float* __restrict__ ymax, float* __restrict__ ymin,
                                                   double* __restrict__ sum, double* __restrict__ sumsq,
                                                   int outc, int l2o4) {
  __shared__ int sidx[16 * 20];
  __shared__ float4v ssum[256], ssq[256];
  int tid = threadIdx.x;
  int base = blockIdx.x * 16;
  for (int i = tid; i < 320; i += 256) sidx[i] = idx[base * 20 + i];
  __syncthreads();
  int tpp = outc >> 2;                      // threads per point
  int o4 = (tid & (tpp - 1)) << 2;
  int rs = tid >> l2o4;
  int R = 256 >> l2o4;
  int twoc = 2 * outc;
  float4v ls = {0.f, 0.f, 0.f, 0.f}, lq = {0.f, 0.f, 0.f, 0.f};
  for (int r = rs; r < 16; r += R) {
    int m = base + r;
    int boff = m & ~1023;
    float4v tv = *(const float4v*)(PT + (size_t)m * twoc + outc + o4);
    float4v vmax = {-INFINITY, -INFINITY, -INFINITY, -INFINITY};
    float4v vmin = {INFINITY, INFINITY, INFINITY, INFINITY};
#pragma unroll
    for (int k = 0; k < 20; ++k) {
      int nb = sidx[r * 20 + k];
      float4v pv = *(const float4v*)(PT + (size_t)(boff + nb) * twoc + o4);
      float4v y = pv + tv;
#pragma unroll
      for (int j = 0; j < 4; ++j) {
        vmax[j] = fmaxf(vmax[j], y[j]);
        vmin[j] = fminf(vmin[j], y[j]);
      }
      ls += y;
      lq += y * y;
    }
    *(float4v*)(ymax + (size_t)m * outc + o4) = vmax;
    *(float4v*)(ymin + (size_t)m * outc + o4) = vmin;
  }
  ssum[tid] = ls; ssq[tid] = lq;
  __syncthreads();
  if (tid < tpp) {
    float4v s = ssum[tid], q = ssq[tid];
    for (int rr = 1; rr < R; ++rr) { s += ssum[tid + rr * tpp]; q += ssq[tid + rr * tpp]; }
#pragma unroll
    for (int j = 0; j < 4; ++j) {
      atomicAdd(&sum[(tid << 2) + j], (double)s[j]);
      atomicAdd(&sumsq[(tid << 2) + j], (double)q[j]);
    }
  }
}

// ---------------- K5: per-channel affine coefficients from stats (f64) ----------------
__global__ __launch_bounds__(256) void coef_kernel(const double* __restrict__ sum,
                                                   const double* __restrict__ sumsq,
                                                   const float* __restrict__ g,
                                                   const float* __restrict__ b,
                                                   float* __restrict__ cA, float* __restrict__ cC,
                                                   int outc, double count) {
  int o = blockIdx.x * 256 + threadIdx.x;
  if (o < outc) {
    double mean = sum[o] / count;
    double var = sumsq[o] / count - mean * mean;
    double a = (double)g[o] / sqrt(var + 1e-5);
    cA[o] = (float)a;
    cC[o] = (float)((double)b[o] - mean * a);
  }
}

// ---------------- K6: pick max/min, affine + LeakyReLU, scatter to H & fused(bf16), float4 ---
__global__ __launch_bounds__(256) void edge_epi(const float* __restrict__ ymax,
                                                const float* __restrict__ ymin,
                                                const float* __restrict__ cA, const float* __restrict__ cC,
                                                float* __restrict__ Hout, unsigned short* __restrict__ fusedb,
                                                int outc, int l2o4, int choff) {
  int i4 = blockIdx.x * 256 + threadIdx.x;   // over 8192*outc/4
  int tpp = outc >> 2;
  int m = i4 >> l2o4;
  int o4 = (i4 & (tpp - 1)) << 2;
  float4v a = *(const float4v*)(cA + o4);
  float4v c = *(const float4v*)(cC + o4);
  float4v vx = *(const float4v*)(ymax + (size_t)i4 * 4);
  float4v vn = *(const float4v*)(ymin + (size_t)i4 * 4);
  float4v y;
  ushort4v fb;
#pragma unroll
  for (int j = 0; j < 4; ++j) {
    float v = (a[j] >= 0.f) ? vx[j] : vn[j];
    float yy = fmaf(a[j], v, c[j]);
    yy = (yy > 0.f) ? yy : 0.2f * yy;
    y[j] = yy;
    fb[j] = f2bf(yy);
  }
  *(float4v*)(Hout + (size_t)i4 * 4) = y;
  *(ushort4v*)(fusedb + (size_t)m * 512 + choff + o4) = fb;
}

// ---------------- K6b: fp32 -> bf16 elementwise ----------------
__global__ __launch_bounds__(256) void cvt_bf16(const float* __restrict__ in,
                                                unsigned short* __restrict__ out, int n) {
  int i = blockIdx.x * 256 + threadIdx.x;
  if (i < n) out[i] = f2bf(in[i]);
}

// ---------------- K7: final GEMM (MFMA bf16) + fused column stats ----------------
__global__ __launch_bounds__(256) void final_gemm_mfma(const unsigned short* __restrict__ A,
                                                       const unsigned short* __restrict__ B,
                                                       float* __restrict__ C,
                                                       double* __restrict__ sum,
                                                       double* __restrict__ sumsq) {
  __shared__ unsigned short As[128 * 32];
  __shared__ unsigned short Bs[128 * 32];
  const int tid = threadIdx.x;
  const int lane = tid & 63;
  const int w = tid >> 6;             // wave 0..3
  const int wm = w >> 1, wn = w & 1;  // 2x2 wave grid, each wave 64x64
  const int rowBase = blockIdx.y * 128;
  const int colBase = blockIdx.x * 128;
  const int quad = lane >> 4;
  const int l15 = lane & 15;

  float4v acc[4][4] = {};

  for (int k0 = 0; k0 < 512; k0 += 32) {
#pragma unroll
    for (int q = 0; q < 2; ++q) {
      int ch = (w * 2 + q) * 64 + lane;          // 0..511, 16B chunks
      int r = ch >> 2, cp = ch & 3;
      const unsigned short* ga = A + (size_t)(rowBase + r) * 512 + k0 + cp * 8;
      const unsigned short* gb = B + (size_t)(colBase + r) * 512 + k0 + cp * 8;
      __builtin_amdgcn_global_load_lds((gptr_t)ga, (lptr_t)(As + (size_t)(w * 2 + q) * 512), 16, 0, 0);
      __builtin_amdgcn_global_load_lds((gptr_t)gb, (lptr_t)(Bs + (size_t)(w * 2 + q) * 512), 16, 0, 0);
    }
    __syncthreads();
    short8 af[4], bf[4];
#pragma unroll
    for (int mi = 0; mi < 4; ++mi)
      af[mi] = *(const short8*)(As + (wm * 64 + mi * 16 + l15) * 32 + quad * 8);
#pragma unroll
    for (int ni = 0; ni < 4; ++ni)
      bf[ni] = *(const short8*)(Bs + (wn * 64 + ni * 16 + l15) * 32 + quad * 8);
#pragma unroll
    for (int mi = 0; mi < 4; ++mi)
#pragma unroll
      for (int ni = 0; ni < 4; ++ni)
        acc[mi][ni] = __builtin_amdgcn_mfma_f32_16x16x32_bf16(af[mi], bf[ni], acc[mi][ni], 0, 0, 0);
    __syncthreads();
  }
  float sc[4] = {0.f, 0.f, 0.f, 0.f}, qc[4] = {0.f, 0.f, 0.f, 0.f};
#pragma unroll
  for (int mi = 0; mi < 4; ++mi)
#pragma unroll
    for (int ni = 0; ni < 4; ++ni)
#pragma unroll
      for (int r = 0; r < 4; ++r) {
        int gm = rowBase + wm * 64 + mi * 16 + quad * 4 + r;
        int gn = colBase + wn * 64 + ni * 16 + l15;
        float v = acc[mi][ni][r];
        C[(size_t)gm * 1024 + gn] = v;
        sc[ni] += v;
        qc[ni] = fmaf(v, v, qc[ni]);
      }
  // fused column stats: LDS reduce 8 contributors per column, then double atomics
  float* fs = (float*)As;   // 128 cols x 8 contributors
  float* fq = (float*)Bs;
#pragma unroll
  for (int ni = 0; ni < 4; ++ni) {
    int cl = wn * 64 + ni * 16 + l15;
    int ct = wm * 4 + quad;
    fs[cl * 8 + ct] = sc[ni];
    fq[cl * 8 + ct] = qc[ni];
  }
  __syncthreads();
  if (tid < 128) {
    float s = 0.f, q = 0.f;
#pragma unroll
    for (int j = 0; j < 8; ++j) { s += fs[tid * 8 + j]; q += fq[tid * 8 + j]; }
    atomicAdd(&sum[colBase + tid], (double)s);
    atomicAdd(&sumsq[colBase + tid], (double)q);
  }
}

// ---------------- K8: final normalize + LeakyReLU (float4) ----------------
__global__ __launch_bounds__(256) void final_epi(const float* __restrict__ yf,
                                                 const float* __restrict__ cA, const float* __restrict__ cC,
                                                 float* __restrict__ out) {
  int i4 = blockIdx.x * 256 + threadIdx.x;    // over 8192*1024/4
  int o4 = (i4 & 255) << 2;
  float4v a = *(const float4v*)(cA + o4);
  float4v c = *(const float4v*)(cC + o4);
  float4v v = *(const float4v*)(yf + (size_t)i4 * 4);
  float4v y;
#pragma unroll
  for (int j = 0; j < 4; ++j) {
    float yy = fmaf(a[j], v[j], c[j]);
    y[j] = (yy > 0.f) ? yy : 0.2f * yy;
  }
  *(float4v*)(out + (size_t)i4 * 4) = y;
}

extern "C" void kernel_launch(void* const* d_in, const int* in_sizes, int n_in,
                              void* d_out, int out_size, void* d_ws, size_t ws_size,
                              hipStream_t stream) {
  const float* x = (const float*)d_in[0];
  const float* W[4]  = {(const float*)d_in[1], (const float*)d_in[4], (const float*)d_in[7], (const float*)d_in[10]};
  const float* g[4]  = {(const float*)d_in[2], (const float*)d_in[5], (const float*)d_in[8], (const float*)d_in[11]};
  const float* bb[4] = {(const float*)d_in[3], (const float*)d_in[6], (const float*)d_in[9], (const float*)d_in[12]};
  const float* Wf  = (const float*)d_in[13];
  const float* gf  = (const float*)d_in[14];
  const float* bfp = (const float*)d_in[15];
  float* out = (float*)d_out;

  char* ws = (char*)d_ws;
  float*  Df    = (float*)(ws + OFF_DF);
  float*  PT    = (float*)(ws + OFF_PT);
  float*  ymax  = (float*)(ws + OFF_YMAX);
  float*  ymin  = (float*)(ws + OFF_YMIN);
  float*  yf    = (float*)(ws + OFF_YF);
  int*    idxb  = (int*)(ws + OFF_IDX);
  float*  Hbuf  = (float*)(ws + OFF_H);
  unsigned short* fusedb = (unsigned short*)(ws + OFF_FUSB);
  unsigned short* wfb    = (unsigned short*)(ws + OFF_WFB);
  float*  xxb   = (float*)(ws + OFF_XX);
  double* stats = (double*)(ws + OFF_STATS);
  float*  coefb = (float*)(ws + OFF_COEF);
  unsigned short* hhi = (unsigned short*)(ws + OFF_HHI);
  unsigned short* hlo = (unsigned short*)(ws + OFF_HLO);
  float*  wcat  = (float*)(ws + OFF_WCAT);

  hipMemsetAsync(stats, 0, 24576, stream);   // zero all stat accumulators (ws is poisoned)
  cvt_bf16<<<(524288 + 255) / 256, 256, 0, stream>>>(Wf, wfb, 524288);

  const int Cin[4]   = {3, 64, 64, 128};
  const int Cout[4]  = {64, 64, 128, 256};
  const int choff[4] = {0, 64, 128, 256};
  const float* Hin = x;
  size_t soff = 0, coff = 0;

  for (int i = 0; i < 4; ++i) {
    int C = Cin[i], oc = Cout[i];
    int l2o4 = (oc == 64) ? 4 : (oc == 128) ? 5 : 6;   // log2(oc/4)
    int Kp = (C == 3) ? 32 : C;                        // padded K for MFMA (dist prefilter)
    int l2kp = (Kp == 32) ? 5 : (Kp == 64) ? 6 : 7;
    double* sum = stats + soff;  double* sumsq = sum + oc;  soff += 2 * (size_t)oc;
    float* cA = coefb + coff;    float* cC = cA + oc;       coff += 2 * (size_t)oc;

    xxf_kernel<<<32, 256, 0, stream>>>(Hin, C, xxb);
    split_bf16<<<(8192 << l2kp) / 256, 256, 0, stream>>>(Hin, C, l2kp, hhi, hlo);
    dist_mfma<<<dim3(8, 8, 8), 256, 0, stream>>>(hhi, hlo, xxb, Df, Kp);
    if (C == 3)       topk_rerank<3><<<2048, 256, 0, stream>>>(Df, Hin, idxb);
    else if (C == 64) topk_rerank<64><<<2048, 256, 0, stream>>>(Df, Hin, idxb);
    else              topk_rerank<128><<<2048, 256, 0, stream>>>(Df, Hin, idxb);
    wcat_kernel<<<(oc * C + 255) / 256, 256, 0, stream>>>(W[i], wcat, oc, C);
    pt_gemm<<<dim3(2 * oc / 64, 128), 256, 0, stream>>>(Hin, wcat, PT, C, 2 * oc);
    edge_reduce<<<512, 256, 0, stream>>>(PT, idxb, ymax, ymin, sum, sumsq, oc, l2o4);
    coef_kernel<<<1, 256, 0, stream>>>(sum, sumsq, g[i], bb[i], cA, cC, oc, 163840.0);
    edge_epi<<<(8192 * oc / 4) / 256, 256, 0, stream>>>(ymax, ymin, cA, cC, Hbuf, fusedb, oc, l2o4, choff[i]);
    Hin = Hbuf;
  }

  double* sumF = stats + soff;  double* sumsqF = sumF + 1024;
  float* cAF = coefb + coff;    float* cCF = cAF + 1024;
  final_gemm_mfma<<<dim3(8, 64), 256, 0, stream>>>(fusedb, wfb, yf, sumF, sumsqF);
  coef_kernel<<<4, 256, 0, stream>>>(sumF, sumsqF, gf, bfp, cAF, cCF, 1024, 8192.0);
  final_epi<<<8192 * 1024 / 4 / 256, 256, 0, stream>>>(yf, cAF, cCF, out);
}

// Round 11
// 518.796 us; speedup vs baseline: 1.2770x; 1.2770x over previous
//
#include <hip/hip_runtime.h>
#include <math.h>

#define TILE 64
#define KC 16

typedef __attribute__((ext_vector_type(8))) short short8;
typedef __attribute__((ext_vector_type(4))) float float4v;
typedef __attribute__((ext_vector_type(4))) unsigned short ushort4v;
typedef const __attribute__((address_space(1))) void* gptr_t;
typedef __attribute__((address_space(3))) void* lptr_t;

// ---------------- workspace layout (bytes) ----------------
#define OFF_DF    0ull          // 8192*1024*4 = 33554432
#define OFF_PT    0ull          // alias: 8192*512*4 = 16777216
#define OFF_YMAX  16777216ull   // alias: 8388608
#define OFF_YMIN  25165824ull   // alias: 8388608
#define OFF_YF    0ull          // alias: 8192*1024*4 = 33554432
#define OFF_IDX   67108864ull   // 655360
#define OFF_H     67764224ull   // 8388608
#define OFF_FUSB  76152832ull   // 8192*512*2 = 8388608 (bf16 fused)
#define OFF_WFB   84541440ull   // 1024*512*2 = 1048576 (bf16 Wf)
#define OFF_XX    85590016ull   // 8192 f32 = 32768
#define OFF_STATS 85917696ull   // 24576
#define OFF_COEF  85942272ull   // 12288
#define OFF_HHI   85954560ull   // 8192*128*2 = 2097152 (bf16 hi plane, Kp<=128)
#define OFF_HLO   88051712ull   // 2097152 (bf16 lo plane)
#define OFF_WCAT  90148864ull   // 512*128*4 = 262144 (fp32 Wcat)

__device__ __forceinline__ unsigned short f2bf(float f) {
  unsigned int u = __float_as_uint(f);
  unsigned int r = (u + 0x7fffu + ((u >> 16) & 1u)) >> 16;
  return (unsigned short)r;
}
__device__ __forceinline__ float bf2f(unsigned short h) {
  return __uint_as_float((unsigned)h << 16);
}

// ---------------- fp32 tiled GEMM core: C(M,N) = A(M,K) * Bw(N,K)^T ----------------
__device__ __forceinline__ void gemm_tile_loop(
    const float* __restrict__ A, const float* __restrict__ Bw,
    int K, int lda, int ldb, int rowBase, int colBase,
    float acc[4][4], float* As, float* Bs)
{
  const int tid = threadIdx.x;
  const int tx = tid & 15, ty = tid >> 4;
  for (int k0 = 0; k0 < K; k0 += KC) {
    for (int l = 0; l < 4; ++l) {
      int flat = tid * 4 + l;           // 0..1023
      int kk = flat & (KC - 1);
      int row = flat >> 4;
      int gk = k0 + kk;
      float av = 0.f, bv = 0.f;
      if (gk < K) {
        av = A[(size_t)(rowBase + row) * lda + gk];
        bv = Bw[(size_t)(colBase + row) * ldb + gk];
      }
      As[kk * TILE + row] = av;
      Bs[kk * TILE + row] = bv;
    }
    __syncthreads();
#pragma unroll
    for (int kk = 0; kk < KC; ++kk) {
      float a0[4], b0[4];
#pragma unroll
      for (int i = 0; i < 4; ++i) a0[i] = As[kk * TILE + ty * 4 + i];
#pragma unroll
      for (int j = 0; j < 4; ++j) b0[j] = Bs[kk * TILE + tx * 4 + j];
#pragma unroll
      for (int i = 0; i < 4; ++i)
#pragma unroll
        for (int j = 0; j < 4; ++j)
          acc[i][j] = fmaf(a0[i], b0[j], acc[i][j]);
    }
    __syncthreads();
  }
}

// ---------------- K0: squared norms per point (f32, prefilter only) ----------------
__global__ __launch_bounds__(256) void xxf_kernel(const float* __restrict__ H, int C,
                                                  float* __restrict__ xx) {
  int m = blockIdx.x * 256 + threadIdx.x;
  if (m < 8192) {
    float s = 0.f;
    for (int c = 0; c < C; ++c) { float h = H[(size_t)m * C + c]; s = fmaf(h, h, s); }
    xx[m] = s;
  }
}

// ---------------- K0b: split H into bf16 hi + lo planes, zero-padded to Kp ----------------
__global__ __launch_bounds__(256) void split_bf16(const float* __restrict__ H, int C, int l2kp,
                                                  unsigned short* __restrict__ hi,
                                                  unsigned short* __restrict__ lo) {
  int i = blockIdx.x * 256 + threadIdx.x;       // over 8192 << l2kp
  int m = i >> l2kp;
  int c = i & ((1 << l2kp) - 1);
  unsigned short h = 0, l = 0;
  if (c < C) {
    float v = H[(size_t)m * C + c];
    h = f2bf(v);
    l = f2bf(v - bf2f(h));
  }
  hi[i] = h;
  lo[i] = l;
}

// ---------------- K1: Gram via split-bf16 MFMA (3 passes) -> neg sq dist (prefilter) ------
__global__ __launch_bounds__(256) void dist_mfma(const unsigned short* __restrict__ Hhi,
                                                 const unsigned short* __restrict__ Hlo,
                                                 const float* __restrict__ xx,
                                                 float* __restrict__ Df, int Kp) {
  __shared__ unsigned short Ash[128 * 32], Asl[128 * 32];
  __shared__ unsigned short Bsh[128 * 32], Bsl[128 * 32];
  const int tid = threadIdx.x;
  const int lane = tid & 63;
  const int w = tid >> 6;
  const int wm = w >> 1, wn = w & 1;
  const int bz = blockIdx.z;
  const int rowBase = bz * 1024 + blockIdx.y * 128;
  const int colBase = bz * 1024 + blockIdx.x * 128;
  const int quad = lane >> 4;
  const int l15 = lane & 15;

  float4v acc[4][4] = {};

  for (int k0 = 0; k0 < Kp; k0 += 32) {
#pragma unroll
    for (int q = 0; q < 2; ++q) {
      int ch = (w * 2 + q) * 64 + lane;          // 0..511 16B-chunks per tile
      int r = ch >> 2, cp = ch & 3;
      size_t offA = (size_t)(rowBase + r) * Kp + k0 + cp * 8;
      size_t offB = (size_t)(colBase + r) * Kp + k0 + cp * 8;
      int seg = (w * 2 + q) * 512;
      __builtin_amdgcn_global_load_lds((gptr_t)(Hhi + offA), (lptr_t)(Ash + seg), 16, 0, 0);
      __builtin_amdgcn_global_load_lds((gptr_t)(Hlo + offA), (lptr_t)(Asl + seg), 16, 0, 0);
      __builtin_amdgcn_global_load_lds((gptr_t)(Hhi + offB), (lptr_t)(Bsh + seg), 16, 0, 0);
      __builtin_amdgcn_global_load_lds((gptr_t)(Hlo + offB), (lptr_t)(Bsl + seg), 16, 0, 0);
    }
    __syncthreads();
    short8 ah[4], al[4], bh[4], bl[4];
#pragma unroll
    for (int mi = 0; mi < 4; ++mi) {
      int ro = (wm * 64 + mi * 16 + l15) * 32 + quad * 8;
      ah[mi] = *(const short8*)(Ash + ro);
      al[mi] = *(const short8*)(Asl + ro);
    }
#pragma unroll
    for (int ni = 0; ni < 4; ++ni) {
      int ro = (wn * 64 + ni * 16 + l15) * 32 + quad * 8;
      bh[ni] = *(const short8*)(Bsh + ro);
      bl[ni] = *(const short8*)(Bsl + ro);
    }
#pragma unroll
    for (int mi = 0; mi < 4; ++mi)
#pragma unroll
      for (int ni = 0; ni < 4; ++ni) {
        acc[mi][ni] = __builtin_amdgcn_mfma_f32_16x16x32_bf16(ah[mi], bh[ni], acc[mi][ni], 0, 0, 0);
        acc[mi][ni] = __builtin_amdgcn_mfma_f32_16x16x32_bf16(ah[mi], bl[ni], acc[mi][ni], 0, 0, 0);
        acc[mi][ni] = __builtin_amdgcn_mfma_f32_16x16x32_bf16(al[mi], bh[ni], acc[mi][ni], 0, 0, 0);
      }
    __syncthreads();
  }
#pragma unroll
  for (int mi = 0; mi < 4; ++mi)
#pragma unroll
    for (int ni = 0; ni < 4; ++ni)
#pragma unroll
      for (int r = 0; r < 4; ++r) {
        int gm = rowBase + wm * 64 + mi * 16 + quad * 4 + r;            // global row
        int gn = blockIdx.x * 128 + wn * 64 + ni * 16 + l15;            // col in batch
        float v = 2.0f * acc[mi][ni][r] - xx[gm] - xx[bz * 1024 + gn];
        Df[(size_t)gm * 1024 + gn] = v;
      }
}

// ---------------- K2: threshold-bisection top-[32..64] superset + exact f64 rank -> top-20 set ----
template<int C>
__global__ __launch_bounds__(256) void topk_rerank(const float* __restrict__ Df,
                                                   const float* __restrict__ H,
                                                   int* __restrict__ idx) {
  __shared__ int    candLds[4][64];
  __shared__ double ndLds[4][64];
  __shared__ int    colLds[4][64];
  const int lane = threadIdx.x & 63;
  const int w = threadIdx.x >> 6;
  const int row = blockIdx.x * 4 + w;              // 0..8191
  const int b = row >> 10;
  const float* drow = Df + (size_t)row * 1024;

  unsigned s[16];
#pragma unroll
  for (int q = 0; q < 4; ++q) {
    float4v v = *(const float4v*)(drow + 256 * q + 4 * lane);
#pragma unroll
    for (int r = 0; r < 4; ++r) {
      unsigned u = __float_as_uint(v[r]);
      s[q * 4 + r] = (u & 0x80000000u) ? ~u : (u | 0x80000000u);
    }
  }

  unsigned p = 0;
  for (int bit = 31; bit >= 0; --bit) {
    unsigned cand = p | (1u << bit);
    int c = 0;
#pragma unroll
    for (int t = 0; t < 16; ++t)
      c += __popcll(__ballot(s[t] > cand));
    if (c >= 32) {
      p = cand;
      if (c <= 64) break;
    }
  }

  const unsigned long long lt = (1ull << lane) - 1ull;
  int base = 0;
#pragma unroll
  for (int t = 0; t < 16; ++t) {
    unsigned long long m = __ballot(s[t] > p);
    if (s[t] > p) {
      int slot = base + (int)__popcll(m & lt);
      if (slot < 64) candLds[w][slot] = 256 * (t >> 2) + 4 * lane + (t & 3);
    }
    base += (int)__popcll(m);
  }
  int nsel = base > 64 ? 64 : base;

  double nd; int col;
  if (lane < nsel) {
    col = candLds[w][lane];
    const float* xi = H + (size_t)row * C;
    const float* xj = H + (size_t)(b * 1024 + col) * C;
    double ssum = 0.0;
    if (C == 3) {
#pragma unroll
      for (int c = 0; c < 3; ++c) {
        double d = (double)xi[c] - (double)xj[c];
        ssum = fma(d, d, ssum);
      }
    } else {
      for (int c = 0; c < C; c += 4) {
        float4v a = *(const float4v*)(xi + c);
        float4v bb = *(const float4v*)(xj + c);
        double d0 = (double)a.x - (double)bb.x;
        double d1 = (double)a.y - (double)bb.y;
        double d2 = (double)a.z - (double)bb.z;
        double d3 = (double)a.w - (double)bb.w;
        ssum = fma(d0, d0, ssum); ssum = fma(d1, d1, ssum);
        ssum = fma(d2, d2, ssum); ssum = fma(d3, d3, ssum);
      }
    }
    nd = -ssum;
  } else {
    nd = -INFINITY; col = 100000 + lane;
  }
  ndLds[w][lane] = nd;
  colLds[w][lane] = col;

  int rank = 0;
#pragma unroll 4
  for (int j = 0; j < 64; ++j) {
    double vj = ndLds[w][j];
    int cj = colLds[w][j];
    rank += (vj > nd || (vj == nd && cj < col)) ? 1 : 0;
  }
  if (rank < 20) idx[(size_t)row * 20 + rank] = col;
}

// ---------------- K3a: Wcat = [W1 ; W2-W1]  (W is (out, 2C) row-major, fp32) ----------------
__global__ __launch_bounds__(256) void wcat_kernel(const float* __restrict__ W,
                                                   float* __restrict__ Wcat, int outc, int C) {
  int i = blockIdx.x * 256 + threadIdx.x;
  if (i < outc * C) {
    int o = i / C, c = i % C;
    float w1 = W[(size_t)o * 2 * C + c];
    float w2 = W[(size_t)o * 2 * C + C + c];
    Wcat[(size_t)o * C + c] = w1;
    Wcat[(size_t)(outc + o) * C + c] = w2 - w1;
  }
}

// ---------------- K3b: PT(M, 2*out) = H(M,C) @ Wcat^T (fp32 — H fidelity critical) ---------
__global__ __launch_bounds__(256) void pt_gemm(const float* __restrict__ A,
                                               const float* __restrict__ Bw,
                                               float* __restrict__ Out, int K, int Nn) {
  __shared__ float As[KC * TILE], Bs[KC * TILE];
  int rowBase = blockIdx.y * 64, colBase = blockIdx.x * 64;
  float acc[4][4] = {};
  gemm_tile_loop(A, Bw, K, K, K, rowBase, colBase, acc, As, Bs);
  int tx = threadIdx.x & 15, ty = threadIdx.x >> 4;
#pragma unroll
  for (int i = 0; i < 4; ++i)
#pragma unroll
    for (int j = 0; j < 4; ++j)
      Out[(size_t)(rowBase + ty * 4 + i) * Nn + colBase + tx * 4 + j] = acc[i][j];
}

// ---------------- K4: gather + max/min over k + channel stats ----------------
// Round-8 proven shape for ALL layers: one block = 16 points x 64 channels;
// scalar per-channel loads (wave reads 256B coalesced, all waves share rows
// pattern within channel slice); grid.y splits channels -> 4x blocks for oc=256.
__global__ __launch_bounds__(256) void edge_reduce(const float* __restrict__ PT,
                                                   const int* __restrict__ idx,
                                                   float* __restrict__ ymax, float* __restrict__ ymin,
                                                   double* __restrict__ sum, double* __restrict__ sumsq,
                                                   int outc) {
  __shared__ int sidx[16 * 20];
  __shared__ float ssum[256], ssq[256];
  int tid = threadIdx.x;
  int base = blockIdx.x * 16;
  int cbase = blockIdx.y * 64;
  for (int i = tid; i < 320; i += 256) sidx[i] = idx[base * 20 + i];
  __syncthreads();
  int o = cbase + (tid & 63);
  int rs = tid >> 6;                    // 0..3
  int twoc = 2 * outc;
  float ls = 0.f, lq = 0.f;
  for (int r = rs; r < 16; r += 4) {
    int m = base + r;
    int boff = m & ~1023;
    float tv = PT[(size_t)m * twoc + outc + o];
    float vmax = -INFINITY, vmin = INFINITY;
#pragma unroll
    for (int k = 0; k < 20; ++k) {
      int nb = sidx[r * 20 + k];
      float p = PT[(size_t)(boff + nb) * twoc + o];
      float y = p + tv;
      vmax = fmaxf(vmax, y);
      vmin = fminf(vmin, y);
      ls += y;
      lq = fmaf(y, y, lq);
    }
    ymax[(size_t)m * outc + o] = vmax;
    ymin[(size_t)m * outc + o] = vmin;
  }
  ssum[tid] = ls; ssq[tid] = lq;
  __syncthreads();
  if (tid < 64) {
    float s = ssum[tid] + ssum[tid + 64] + ssum[tid + 128] + ssum[tid + 192];
    float q = ssq[tid] + ssq[tid + 64] + ssq[tid + 128] + ssq[tid + 192];
    atomicAdd(&sum[cbase + tid], (double)s);
    atomicAdd(&sumsq[cbase + tid], (double)q);
  }
}

// ---------------- K5: per-channel affine coefficients from stats (f64) ----------------
__global__ __launch_bounds__(256) void coef_kernel(const double* __restrict__ sum,
                                                   const double* __restrict__ sumsq,
                                                   const float* __restrict__ g,
                                                   const float* __restrict__ b,
                                                   float* __restrict__ cA, float* __restrict__ cC,
                                                   int outc, double count) {
  int o = blockIdx.x * 256 + threadIdx.x;
  if (o < outc) {
    double mean = sum[o] / count;
    double var = sumsq[o] / count - mean * mean;
    double a = (double)g[o] / sqrt(var + 1e-5);
    cA[o] = (float)a;
    cC[o] = (float)((double)b[o] - mean * a);
  }
}

// ---------------- K6: pick max/min, affine + LeakyReLU, scatter to H & fused(bf16), float4 ---
__global__ __launch_bounds__(256) void edge_epi(const float* __restrict__ ymax,
                                                const float* __restrict__ ymin,
                                                const float* __restrict__ cA, const float* __restrict__ cC,
                                                float* __restrict__ Hout, unsigned short* __restrict__ fusedb,
                                                int outc, int l2o4, int choff) {
  int i4 = blockIdx.x * 256 + threadIdx.x;   // over 8192*outc/4
  int tpp = outc >> 2;
  int m = i4 >> l2o4;
  int o4 = (i4 & (tpp - 1)) << 2;
  float4v a = *(const float4v*)(cA + o4);
  float4v c = *(const float4v*)(cC + o4);
  float4v vx = *(const float4v*)(ymax + (size_t)i4 * 4);
  float4v vn = *(const float4v*)(ymin + (size_t)i4 * 4);
  float4v y;
  ushort4v fb;
#pragma unroll
  for (int j = 0; j < 4; ++j) {
    float v = (a[j] >= 0.f) ? vx[j] : vn[j];
    float yy = fmaf(a[j], v, c[j]);
    yy = (yy > 0.f) ? yy : 0.2f * yy;
    y[j] = yy;
    fb[j] = f2bf(yy);
  }
  *(float4v*)(Hout + (size_t)i4 * 4) = y;
  *(ushort4v*)(fusedb + (size_t)m * 512 + choff + o4) = fb;
}

// ---------------- K6b: fp32 -> bf16 elementwise ----------------
__global__ __launch_bounds__(256) void cvt_bf16(const float* __restrict__ in,
                                                unsigned short* __restrict__ out, int n) {
  int i = blockIdx.x * 256 + threadIdx.x;
  if (i < n) out[i] = f2bf(in[i]);
}

// ---------------- K7: final GEMM (MFMA bf16) + fused column stats ----------------
__global__ __launch_bounds__(256) void final_gemm_mfma(const unsigned short* __restrict__ A,
                                                       const unsigned short* __restrict__ B,
                                                       float* __restrict__ C,
                                                       double* __restrict__ sum,
                                                       double* __restrict__ sumsq) {
  __shared__ unsigned short As[128 * 32];
  __shared__ unsigned short Bs[128 * 32];
  const int tid = threadIdx.x;
  const int lane = tid & 63;
  const int w = tid >> 6;             // wave 0..3
  const int wm = w >> 1, wn = w & 1;  // 2x2 wave grid, each wave 64x64
  const int rowBase = blockIdx.y * 128;
  const int colBase = blockIdx.x * 128;
  const int quad = lane >> 4;
  const int l15 = lane & 15;

  float4v acc[4][4] = {};

  for (int k0 = 0; k0 < 512; k0 += 32) {
#pragma unroll
    for (int q = 0; q < 2; ++q) {
      int ch = (w * 2 + q) * 64 + lane;          // 0..511, 16B chunks
      int r = ch >> 2, cp = ch & 3;
      const unsigned short* ga = A + (size_t)(rowBase + r) * 512 + k0 + cp * 8;
      const unsigned short* gb = B + (size_t)(colBase + r) * 512 + k0 + cp * 8;
      __builtin_amdgcn_global_load_lds((gptr_t)ga, (lptr_t)(As + (size_t)(w * 2 + q) * 512), 16, 0, 0);
      __builtin_amdgcn_global_load_lds((gptr_t)gb, (lptr_t)(Bs + (size_t)(w * 2 + q) * 512), 16, 0, 0);
    }
    __syncthreads();
    short8 af[4], bf[4];
#pragma unroll
    for (int mi = 0; mi < 4; ++mi)
      af[mi] = *(const short8*)(As + (wm * 64 + mi * 16 + l15) * 32 + quad * 8);
#pragma unroll
    for (int ni = 0; ni < 4; ++ni)
      bf[ni] = *(const short8*)(Bs + (wn * 64 + ni * 16 + l15) * 32 + quad * 8);
#pragma unroll
    for (int mi = 0; mi < 4; ++mi)
#pragma unroll
      for (int ni = 0; ni < 4; ++ni)
        acc[mi][ni] = __builtin_amdgcn_mfma_f32_16x16x32_bf16(af[mi], bf[ni], acc[mi][ni], 0, 0, 0);
    __syncthreads();
  }
  float sc[4] = {0.f, 0.f, 0.f, 0.f}, qc[4] = {0.f, 0.f, 0.f, 0.f};
#pragma unroll
  for (int mi = 0; mi < 4; ++mi)
#pragma unroll
    for (int ni = 0; ni < 4; ++ni)
#pragma unroll
      for (int r = 0; r < 4; ++r) {
        int gm = rowBase + wm * 64 + mi * 16 + quad * 4 + r;
        int gn = colBase + wn * 64 + ni * 16 + l15;
        float v = acc[mi][ni][r];
        C[(size_t)gm * 1024 + gn] = v;
        sc[ni] += v;
        qc[ni] = fmaf(v, v, qc[ni]);
      }
  // fused column stats: LDS reduce 8 contributors per column, then double atomics
  float* fs = (float*)As;   // 128 cols x 8 contributors
  float* fq = (float*)Bs;
#pragma unroll
  for (int ni = 0; ni < 4; ++ni) {
    int cl = wn * 64 + ni * 16 + l15;
    int ct = wm * 4 + quad;
    fs[cl * 8 + ct] = sc[ni];
    fq[cl * 8 + ct] = qc[ni];
  }
  __syncthreads();
  if (tid < 128) {
    float s = 0.f, q = 0.f;
#pragma unroll
    for (int j = 0; j < 8; ++j) { s += fs[tid * 8 + j]; q += fq[tid * 8 + j]; }
    atomicAdd(&sum[colBase + tid], (double)s);
    atomicAdd(&sumsq[colBase + tid], (double)q);
  }
}

// ---------------- K8: final normalize + LeakyReLU (float4) ----------------
__global__ __launch_bounds__(256) void final_epi(const float* __restrict__ yf,
                                                 const float* __restrict__ cA, const float* __restrict__ cC,
                                                 float* __restrict__ out) {
  int i4 = blockIdx.x * 256 + threadIdx.x;    // over 8192*1024/4
  int o4 = (i4 & 255) << 2;
  float4v a = *(const float4v*)(cA + o4);
  float4v c = *(const float4v*)(cC + o4);
  float4v v = *(const float4v*)(yf + (size_t)i4 * 4);
  float4v y;
#pragma unroll
  for (int j = 0; j < 4; ++j) {
    float yy = fmaf(a[j], v[j], c[j]);
    y[j] = (yy > 0.f) ? yy : 0.2f * yy;
  }
  *(float4v*)(out + (size_t)i4 * 4) = y;
}

extern "C" void kernel_launch(void* const* d_in, const int* in_sizes, int n_in,
                              void* d_out, int out_size, void* d_ws, size_t ws_size,
                              hipStream_t stream) {
  const float* x = (const float*)d_in[0];
  const float* W[4]  = {(const float*)d_in[1], (const float*)d_in[4], (const float*)d_in[7], (const float*)d_in[10]};
  const float* g[4]  = {(const float*)d_in[2], (const float*)d_in[5], (const float*)d_in[8], (const float*)d_in[11]};
  const float* bb[4] = {(const float*)d_in[3], (const float*)d_in[6], (const float*)d_in[9], (const float*)d_in[12]};
  const float* Wf  = (const float*)d_in[13];
  const float* gf  = (const float*)d_in[14];
  const float* bfp = (const float*)d_in[15];
  float* out = (float*)d_out;

  char* ws = (char*)d_ws;
  float*  Df    = (float*)(ws + OFF_DF);
  float*  PT    = (float*)(ws + OFF_PT);
  float*  ymax  = (float*)(ws + OFF_YMAX);
  float*  ymin  = (float*)(ws + OFF_YMIN);
  float*  yf    = (float*)(ws + OFF_YF);
  int*    idxb  = (int*)(ws + OFF_IDX);
  float*  Hbuf  = (float*)(ws + OFF_H);
  unsigned short* fusedb = (unsigned short*)(ws + OFF_FUSB);
  unsigned short* wfb    = (unsigned short*)(ws + OFF_WFB);
  float*  xxb   = (float*)(ws + OFF_XX);
  double* stats = (double*)(ws + OFF_STATS);
  float*  coefb = (float*)(ws + OFF_COEF);
  unsigned short* hhi = (unsigned short*)(ws + OFF_HHI);
  unsigned short* hlo = (unsigned short*)(ws + OFF_HLO);
  float*  wcat  = (float*)(ws + OFF_WCAT);

  hipMemsetAsync(stats, 0, 24576, stream);   // zero all stat accumulators (ws is poisoned)
  cvt_bf16<<<(524288 + 255) / 256, 256, 0, stream>>>(Wf, wfb, 524288);

  const int Cin[4]   = {3, 64, 64, 128};
  const int Cout[4]  = {64, 64, 128, 256};
  const int choff[4] = {0, 64, 128, 256};
  const float* Hin = x;
  size_t soff = 0, coff = 0;

  for (int i = 0; i < 4; ++i) {
    int C = Cin[i], oc = Cout[i];
    int l2o4 = (oc == 64) ? 4 : (oc == 128) ? 5 : 6;   // log2(oc/4)
    int Kp = (C == 3) ? 32 : C;                        // padded K for MFMA (dist prefilter)
    int l2kp = (Kp == 32) ? 5 : (Kp == 64) ? 6 : 7;
    double* sum = stats + soff;  double* sumsq = sum + oc;  soff += 2 * (size_t)oc;
    float* cA = coefb + coff;    float* cC = cA + oc;       coff += 2 * (size_t)oc;

    xxf_kernel<<<32, 256, 0, stream>>>(Hin, C, xxb);
    split_bf16<<<(8192 << l2kp) / 256, 256, 0, stream>>>(Hin, C, l2kp, hhi, hlo);
    dist_mfma<<<dim3(8, 8, 8), 256, 0, stream>>>(hhi, hlo, xxb, Df, Kp);
    if (C == 3)       topk_rerank<3><<<2048, 256, 0, stream>>>(Df, Hin, idxb);
    else if (C == 64) topk_rerank<64><<<2048, 256, 0, stream>>>(Df, Hin, idxb);
    else              topk_rerank<128><<<2048, 256, 0, stream>>>(Df, Hin, idxb);
    wcat_kernel<<<(oc * C + 255) / 256, 256, 0, stream>>>(W[i], wcat, oc, C);
    pt_gemm<<<dim3(2 * oc / 64, 128), 256, 0, stream>>>(Hin, wcat, PT, C, 2 * oc);
    edge_reduce<<<dim3(512, oc / 64), 256, 0, stream>>>(PT, idxb, ymax, ymin, sum, sumsq, oc);
    coef_kernel<<<1, 256, 0, stream>>>(sum, sumsq, g[i], bb[i], cA, cC, oc, 163840.0);
    edge_epi<<<(8192 * oc / 4) / 256, 256, 0, stream>>>(ymax, ymin, cA, cC, Hbuf, fusedb, oc, l2o4, choff[i]);
    Hin = Hbuf;
  }

  double* sumF = stats + soff;  double* sumsqF = sumF + 1024;
  float* cAF = coefb + coff;    float* cCF = cAF + 1024;
  final_gemm_mfma<<<dim3(8, 64), 256, 0, stream>>>(fusedb, wfb, yf, sumF, sumsqF);
  coef_kernel<<<4, 256, 0, stream>>>(sumF, sumsqF, gf, bfp, cAF, cCF, 1024, 8192.0);
  final_epi<<<8192 * 1024 / 4 / 256, 256, 0, stream>>>(yf, cAF, cCF, out);
}